// Round 3
// baseline (3191.551 us; speedup 1.0000x reference)
//
#include <hip/hip_runtime.h>
#include <math.h>

#define BB 64
#define NN 8192
#define LL 64
#define KK 20
#define TILE 128
#define NT 4        // tiles per block
#define CHUNKS 16   // blocks per batch entry: CHUNKS*NT*TILE == NN
#define ZS 68       // z_s row stride (floats): 272 B, 16B-aligned, bank-rotated
#define PS 132      // pt row stride: rows are 128 wide (one slot per tile row)!

// ---------------------------------------------------------------------------
// ws layout (floats):
//   IA   : [64*64]            @ 0
//   M    : [64*64]            @ 4096
//   bias : [B*K]              @ 8192
//   nk   : [B*K]              @ 9472
//   macc : [B*K*L]            @ 10752
// total 92672 floats = 370,688 B
// ---------------------------------------------------------------------------

// Compute IA = I - A and M = inv(I + IA @ IA^T) via Gauss-Jordan (SPD).
__global__ __launch_bounds__(256) void k_setup(const float* __restrict__ A,
                                               float* __restrict__ IA,
                                               float* __restrict__ M) {
    __shared__ __align__(16) float ia[64][64];
    __shared__ __align__(16) float aug[64][130];
    int t = threadIdx.x;
    for (int i = t; i < 4096; i += 256) {
        int r = i >> 6, c = i & 63;
        float v = (r == c ? 1.0f : 0.0f) - A[i];
        ia[r][c] = v;
        IA[i] = v;
    }
    __syncthreads();
    for (int i = t; i < 4096; i += 256) {
        int r = i >> 6, c = i & 63;
        float s = (r == c) ? 1.0f : 0.0f;
        for (int l = 0; l < 64; ++l) s += ia[r][l] * ia[c][l];
        aug[r][c] = s;
        aug[r][64 + c] = (r == c) ? 1.0f : 0.0f;
    }
    __syncthreads();
    int r = t >> 2;              // 4 threads per row
    int c0 = (t & 3) * 32;       // 32 cols each -> covers 128 cols
    for (int k = 0; k < 64; ++k) {
        float pivinv = 1.0f / aug[k][k];
        float f = aug[r][k] * pivinv;   // read before any write this iter
        __syncthreads();
        if (r != k) {
            #pragma unroll 8
            for (int c = c0; c < c0 + 32; ++c) aug[r][c] -= f * aug[k][c];
        }
        __syncthreads();
        if (r == k) {
            #pragma unroll 8
            for (int c = c0; c < c0 + 32; ++c) aug[r][c] *= pivinv;
        }
        __syncthreads();
    }
    for (int i = t; i < 4096; i += 256) {
        int rr = i >> 6, c = i & 63;
        M[i] = aug[rr][64 + c];
    }
}

// Per (b,k): mean = z[b, idx, :] @ M ; write bias; zero accumulators.
__global__ __launch_bounds__(64) void k_init(const float* __restrict__ z,
                                             const int* __restrict__ idxs,
                                             const float* __restrict__ M,
                                             const float* __restrict__ IA,
                                             float* __restrict__ out_mean,
                                             float* __restrict__ bias,
                                             float* __restrict__ nk,
                                             float* __restrict__ macc) {
    int k = blockIdx.x, b = blockIdx.y;
    int l = threadIdx.x;
    int bk = b * KK + k;
    __shared__ float srow[64];
    __shared__ float smean[64];
    int idx = idxs[bk];
    srow[l] = z[((size_t)b * NN + idx) * LL + l];
    __syncthreads();
    float nm = 0.f;
    #pragma unroll 8
    for (int m = 0; m < 64; ++m) nm += srow[m] * M[m * 64 + l];
    out_mean[(size_t)bk * LL + l] = nm;
    smean[l] = nm;
    __syncthreads();
    float cm = 0.f;
    #pragma unroll 8
    for (int m = 0; m < 64; ++m) cm += smean[m] * IA[m * 64 + l];
    float sqm = nm * nm;
    float sqc = cm * cm;
    for (int off = 32; off > 0; off >>= 1) {
        sqm += __shfl_down(sqm, off);
        sqc += __shfl_down(sqc, off);
    }
    if (l == 0) {
        bias[bk] = logf(1.0f / KK) - 0.5f * (sqm + sqc);
        nk[bk] = 0.f;
    }
    macc[(size_t)bk * LL + l] = 0.f;
}

// Fused EM pass, persistent-chunk version.
// Grid: (CHUNKS, BB) x 256 threads. Each block handles NT tiles of 128 rows.
// Per tile: phase A = logits+softmax fully in registers (row-per-lane,
// k split across lane halves, shfl_xor(32) merge); post exchanged via pt;
// phase B = column-accumulate into per-thread pacc[20] (carried over tiles).
// Next tile's z is prefetched into registers during compute (T14 split).
// End: cross-wave LDS reduce, then ONE atomicAdd per (k,l) per block.
__global__ __launch_bounds__(256) void k_empass(const float* __restrict__ z,
                                                const float* __restrict__ mean,
                                                const float* __restrict__ bias,
                                                float* __restrict__ nk,
                                                float* __restrict__ macc) {
    __shared__ __align__(16) float z_s[TILE][ZS];
    __shared__ __align__(16) float mean_s[KK][ZS];
    __shared__ __align__(16) float pt[KK][PS];
    __shared__ float bias_s[KK];
    __shared__ float nkred[4][KK];
    int t = threadIdx.x;
    int lane = t & 63;
    int q = t >> 6;             // wave id 0..3
    int j = lane & 31;          // row-in-wave
    int h = lane >> 5;          // k half: 0 -> k 0..9, 1 -> k 10..19
    int myrow = q * 32 + j;
    int b = blockIdx.y;
    size_t zbase = ((size_t)b * NN + (size_t)blockIdx.x * (TILE * NT)) * LL;

    for (int i = t; i < KK * LL; i += 256)
        mean_s[i >> 6][i & 63] = mean[(size_t)b * KK * LL + i];
    if (t < KK) bias_s[t] = bias[b * KK + t];

    const float4* zg = (const float4*)(z + zbase);
    float4 pf[8];
    #pragma unroll
    for (int u = 0; u < 8; ++u) pf[u] = zg[u * 256 + t];
    #pragma unroll
    for (int u = 0; u < 8; ++u) {
        int f = u * 256 + t;
        *(float4*)&z_s[f >> 4][(f & 15) * 4] = pf[u];
    }
    __syncthreads();

    float pacc[KK];
    #pragma unroll
    for (int k = 0; k < KK; ++k) pacc[k] = 0.f;
    float nkp[10];
    #pragma unroll
    for (int i = 0; i < 10; ++i) nkp[i] = 0.f;

    for (int tt = 0; tt < NT; ++tt) {
        // prefetch next tile into registers (latency hides under A+B)
        if (tt + 1 < NT) {
            #pragma unroll
            for (int u = 0; u < 8; ++u) pf[u] = zg[(tt + 1) * 2048 + u * 256 + t];
        }
        // ---- phase A: logits + softmax, in registers ----
        float lg[10];
        #pragma unroll
        for (int i = 0; i < 10; ++i) lg[i] = bias_s[h * 10 + i];
        #pragma unroll
        for (int c = 0; c < 64; c += 8) {
            float4 a0 = *(const float4*)&z_s[myrow][c];
            float4 a1 = *(const float4*)&z_s[myrow][c + 4];
            #pragma unroll
            for (int i = 0; i < 10; ++i) {
                const float* mrow = mean_s[h * 10 + i];
                float4 m0 = *(const float4*)&mrow[c];
                float4 m1 = *(const float4*)&mrow[c + 4];
                lg[i] += a0.x * m0.x + a0.y * m0.y + a0.z * m0.z + a0.w * m0.w
                       + a1.x * m1.x + a1.y * m1.y + a1.z * m1.z + a1.w * m1.w;
            }
        }
        float mx = lg[0];
        #pragma unroll
        for (int i = 1; i < 10; ++i) mx = fmaxf(mx, lg[i]);
        mx = fmaxf(mx, __shfl_xor(mx, 32));
        float s = 0.f;
        #pragma unroll
        for (int i = 0; i < 10; ++i) { lg[i] = __expf(lg[i] - mx); s += lg[i]; }
        s += __shfl_xor(s, 32);
        float invs = 1.0f / s;
        #pragma unroll
        for (int i = 0; i < 10; ++i) {
            lg[i] *= invs;           // posterior
            nkp[i] += lg[i];
            pt[h * 10 + i][myrow] = lg[i];
        }
        __syncthreads();
        // ---- phase B: wave q accumulates rows q*32..+31, lane = column ----
        int rb = q * 32;
        for (int r = rb; r < rb + 32; r += 4) {
            float zv0 = z_s[r][lane];
            float zv1 = z_s[r + 1][lane];
            float zv2 = z_s[r + 2][lane];
            float zv3 = z_s[r + 3][lane];
            #pragma unroll
            for (int k = 0; k < KK; ++k) {
                float4 p = *(const float4*)&pt[k][r];
                pacc[k] += p.x * zv0 + p.y * zv1 + p.z * zv2 + p.w * zv3;
            }
        }
        __syncthreads();
        // ---- write prefetched tile, then barrier before next phase A ----
        if (tt + 1 < NT) {
            #pragma unroll
            for (int u = 0; u < 8; ++u) {
                int f = u * 256 + t;
                *(float4*)&z_s[f >> 4][(f & 15) * 4] = pf[u];
            }
        }
        __syncthreads();
    }

    // ---- cross-wave reduce (reuse z_s region), single atomic per slot ----
    float* red = &z_s[0][0];    // 4*20*64 = 5120 floats <= 128*68
    #pragma unroll
    for (int k = 0; k < KK; ++k) red[(q * KK + k) * 64 + lane] = pacc[k];
    #pragma unroll
    for (int off = 16; off >= 1; off >>= 1) {
        #pragma unroll
        for (int i = 0; i < 10; ++i) nkp[i] += __shfl_down(nkp[i], off);
    }
    if (j == 0) {
        #pragma unroll
        for (int i = 0; i < 10; ++i) nkred[q][h * 10 + i] = nkp[i];
    }
    __syncthreads();
    for (int idx = t; idx < KK * 64; idx += 256) {
        int k = idx >> 6, l = idx & 63;
        float sum = red[k * 64 + l] + red[(KK + k) * 64 + l]
                  + red[(2 * KK + k) * 64 + l] + red[(3 * KK + k) * 64 + l];
        atomicAdd(&macc[((size_t)b * KK + k) * LL + l], sum);
    }
    if (t < KK) {
        float sum = nkred[0][t] + nkred[1][t] + nkred[2][t] + nkred[3][t];
        atomicAdd(&nk[b * KK + t], sum);
    }
}

// Per (b,k): pi = Nk/N, mean = (macc/Nk) @ M, bias for next iter, re-zero acc.
__global__ __launch_bounds__(64) void k_final(const float* __restrict__ Mm,
                                              const float* __restrict__ IA,
                                              float* __restrict__ nk,
                                              float* __restrict__ macc,
                                              float* __restrict__ bias,
                                              float* __restrict__ out_pi,
                                              float* __restrict__ out_mean,
                                              float* __restrict__ out_trace) {
    int k = blockIdx.x, b = blockIdx.y;
    int l = threadIdx.x;
    int bk = b * KK + k;
    __shared__ float sraw[64];
    __shared__ float smean[64];
    float Nk = nk[bk];
    if (Nk == 0.f) Nk = 1e-22f;
    float pi = Nk / (float)NN;
    float raw = macc[(size_t)bk * LL + l] / Nk;
    sraw[l] = raw;
    __syncthreads();
    float nm = 0.f;
    #pragma unroll 8
    for (int m = 0; m < 64; ++m) nm += sraw[m] * Mm[m * 64 + l];
    out_mean[(size_t)bk * LL + l] = nm;
    smean[l] = nm;
    __syncthreads();
    float cm = 0.f;
    #pragma unroll 8
    for (int m = 0; m < 64; ++m) cm += smean[m] * IA[m * 64 + l];
    float sqm = nm * nm;
    float sqc = cm * cm;
    for (int off = 32; off > 0; off >>= 1) {
        sqm += __shfl_down(sqm, off);
        sqc += __shfl_down(sqc, off);
    }
    if (l == 0) {
        bias[bk] = logf(pi) - 0.5f * (sqm + sqc);
        out_pi[bk] = pi;
        out_trace[bk] = 1.0f;
        nk[bk] = 0.f;
    }
    macc[(size_t)bk * LL + l] = 0.f;
}

extern "C" void kernel_launch(void* const* d_in, const int* in_sizes, int n_in,
                              void* d_out, int out_size, void* d_ws, size_t ws_size,
                              hipStream_t stream) {
    const float* z = (const float*)d_in[0];
    const float* A = (const float*)d_in[1];
    const int* idxs = (const int*)d_in[2];

    float* out_pi = (float*)d_out;
    float* out_mean = out_pi + BB * KK;
    float* out_trace = out_mean + (size_t)BB * KK * LL;

    float* ws = (float*)d_ws;
    float* IA = ws;
    float* M = ws + 4096;
    float* bias = ws + 8192;
    float* nk = ws + 9472;
    float* macc = ws + 10752;

    k_setup<<<1, 256, 0, stream>>>(A, IA, M);
    k_init<<<dim3(KK, BB), 64, 0, stream>>>(z, idxs, M, IA, out_mean, bias, nk, macc);
    for (int it = 0; it < 5; ++it) {
        k_empass<<<dim3(CHUNKS, BB), 256, 0, stream>>>(z, out_mean, bias, nk, macc);
        k_final<<<dim3(KK, BB), 64, 0, stream>>>(M, IA, nk, macc, bias, out_pi, out_mean, out_trace);
    }
}

// Round 4
// 581.289 us; speedup vs baseline: 5.4905x; 5.4905x over previous
//
#include <hip/hip_runtime.h>
#include <math.h>

#define BB 64
#define NN 8192
#define LL 64
#define KK 20
#define TILE 128
#define NT 4        // tiles per block
#define CHUNKS 16   // blocks per batch entry: CHUNKS*NT*TILE == NN
#define ZS 68       // z_s row stride (floats): 272 B, 16B-aligned, bank-rotated
#define PS 132      // pt row stride: rows are 128 wide (one slot per tile row)

// ---------------------------------------------------------------------------
// ws layout (floats):
//   IA   : [64*64]            @ 0
//   M    : [64*64]            @ 4096
//   bias : [B*K]              @ 8192
//   nk   : [B*K]              @ 9472
//   macc : [B*K*L]            @ 10752
// ---------------------------------------------------------------------------

// Compute IA = I - A and M = inv(I + IA @ IA^T) via Gauss-Jordan (SPD).
__global__ __launch_bounds__(256) void k_setup(const float* __restrict__ A,
                                               float* __restrict__ IA,
                                               float* __restrict__ M) {
    __shared__ __align__(16) float ia[64][64];
    __shared__ __align__(16) float aug[64][130];
    int t = threadIdx.x;
    for (int i = t; i < 4096; i += 256) {
        int r = i >> 6, c = i & 63;
        float v = (r == c ? 1.0f : 0.0f) - A[i];
        ia[r][c] = v;
        IA[i] = v;
    }
    __syncthreads();
    for (int i = t; i < 4096; i += 256) {
        int r = i >> 6, c = i & 63;
        float s = (r == c) ? 1.0f : 0.0f;
        for (int l = 0; l < 64; ++l) s += ia[r][l] * ia[c][l];
        aug[r][c] = s;
        aug[r][64 + c] = (r == c) ? 1.0f : 0.0f;
    }
    __syncthreads();
    int r = t >> 2;              // 4 threads per row
    int c0 = (t & 3) * 32;       // 32 cols each -> covers 128 cols
    for (int k = 0; k < 64; ++k) {
        float pivinv = 1.0f / aug[k][k];
        float f = aug[r][k] * pivinv;   // read before any write this iter
        __syncthreads();
        if (r != k) {
            #pragma unroll 8
            for (int c = c0; c < c0 + 32; ++c) aug[r][c] -= f * aug[k][c];
        }
        __syncthreads();
        if (r == k) {
            #pragma unroll 8
            for (int c = c0; c < c0 + 32; ++c) aug[r][c] *= pivinv;
        }
        __syncthreads();
    }
    for (int i = t; i < 4096; i += 256) {
        int rr = i >> 6, c = i & 63;
        M[i] = aug[rr][64 + c];
    }
}

// Per (b,k): mean = z[b, idx, :] @ M ; write bias; zero accumulators.
__global__ __launch_bounds__(64) void k_init(const float* __restrict__ z,
                                             const int* __restrict__ idxs,
                                             const float* __restrict__ M,
                                             const float* __restrict__ IA,
                                             float* __restrict__ out_mean,
                                             float* __restrict__ bias,
                                             float* __restrict__ nk,
                                             float* __restrict__ macc) {
    int k = blockIdx.x, b = blockIdx.y;
    int l = threadIdx.x;
    int bk = b * KK + k;
    __shared__ float srow[64];
    __shared__ float smean[64];
    int idx = idxs[bk];
    srow[l] = z[((size_t)b * NN + idx) * LL + l];
    __syncthreads();
    float nm = 0.f;
    #pragma unroll 8
    for (int m = 0; m < 64; ++m) nm += srow[m] * M[m * 64 + l];
    out_mean[(size_t)bk * LL + l] = nm;
    smean[l] = nm;
    __syncthreads();
    float cm = 0.f;
    #pragma unroll 8
    for (int m = 0; m < 64; ++m) cm += smean[m] * IA[m * 64 + l];
    float sqm = nm * nm;
    float sqc = cm * cm;
    for (int off = 32; off > 0; off >>= 1) {
        sqm += __shfl_down(sqm, off);
        sqc += __shfl_down(sqc, off);
    }
    if (l == 0) {
        bias[bk] = logf(1.0f / KK) - 0.5f * (sqm + sqc);
        nk[bk] = 0.f;
    }
    macc[(size_t)bk * LL + l] = 0.f;
}

// Fused EM pass, persistent-chunk version (no register prefetch).
// Grid: (CHUNKS, BB) x 256 threads. Each block handles NT tiles of 128 rows.
__global__ __launch_bounds__(256, 4) void k_empass(const float* __restrict__ z,
                                                   const float* __restrict__ mean,
                                                   const float* __restrict__ bias,
                                                   float* __restrict__ nk,
                                                   float* __restrict__ macc) {
    __shared__ __align__(16) float z_s[TILE][ZS];
    __shared__ __align__(16) float mean_s[KK][ZS];
    __shared__ __align__(16) float pt[KK][PS];
    __shared__ float bias_s[KK];
    __shared__ float nkred[4][KK];
    int t = threadIdx.x;
    int lane = t & 63;
    int q = t >> 6;             // wave id 0..3
    int j = lane & 31;          // row-in-wave
    int h = lane >> 5;          // k half: 0 -> k 0..9, 1 -> k 10..19
    int myrow = q * 32 + j;
    int b = blockIdx.y;
    size_t zbase = ((size_t)b * NN + (size_t)blockIdx.x * (TILE * NT)) * LL;

    for (int i = t; i < KK * LL; i += 256)
        mean_s[i >> 6][i & 63] = mean[(size_t)b * KK * LL + i];
    if (t < KK) bias_s[t] = bias[b * KK + t];

    const float4* zg = (const float4*)(z + zbase);

    float pacc[KK];
    #pragma unroll
    for (int k = 0; k < KK; ++k) pacc[k] = 0.f;
    float nkp[10];
    #pragma unroll
    for (int i = 0; i < 10; ++i) nkp[i] = 0.f;

    for (int tt = 0; tt < NT; ++tt) {
        if (tt > 0) __syncthreads();   // protect z_s/pt overwrite vs prev phase B
        // ---- stage tile tt: global -> LDS (8 float4 per thread) ----
        #pragma unroll
        for (int u = 0; u < 8; ++u) {
            float4 v = zg[tt * 2048 + u * 256 + t];
            int f = u * 256 + t;
            *(float4*)&z_s[f >> 4][(f & 15) * 4] = v;
        }
        __syncthreads();
        // ---- phase A: logits + softmax, in registers ----
        float lg[10];
        #pragma unroll
        for (int i = 0; i < 10; ++i) lg[i] = bias_s[h * 10 + i];
        #pragma unroll 2
        for (int c = 0; c < 64; c += 8) {
            float4 a0 = *(const float4*)&z_s[myrow][c];
            float4 a1 = *(const float4*)&z_s[myrow][c + 4];
            #pragma unroll
            for (int i = 0; i < 10; ++i) {
                const float* mrow = mean_s[h * 10 + i];
                float4 m0 = *(const float4*)&mrow[c];
                float4 m1 = *(const float4*)&mrow[c + 4];
                lg[i] += a0.x * m0.x + a0.y * m0.y + a0.z * m0.z + a0.w * m0.w
                       + a1.x * m1.x + a1.y * m1.y + a1.z * m1.z + a1.w * m1.w;
            }
        }
        float mx = lg[0];
        #pragma unroll
        for (int i = 1; i < 10; ++i) mx = fmaxf(mx, lg[i]);
        mx = fmaxf(mx, __shfl_xor(mx, 32));
        float s = 0.f;
        #pragma unroll
        for (int i = 0; i < 10; ++i) { lg[i] = __expf(lg[i] - mx); s += lg[i]; }
        s += __shfl_xor(s, 32);
        float invs = 1.0f / s;
        #pragma unroll
        for (int i = 0; i < 10; ++i) {
            lg[i] *= invs;           // posterior
            nkp[i] += lg[i];
            pt[h * 10 + i][myrow] = lg[i];
        }
        __syncthreads();
        // ---- phase B: wave q accumulates rows q*32..+31, lane = column ----
        int rb = q * 32;
        #pragma unroll 2
        for (int r = rb; r < rb + 32; r += 4) {
            float zv0 = z_s[r][lane];
            float zv1 = z_s[r + 1][lane];
            float zv2 = z_s[r + 2][lane];
            float zv3 = z_s[r + 3][lane];
            #pragma unroll
            for (int k = 0; k < KK; ++k) {
                float4 p = *(const float4*)&pt[k][r];
                pacc[k] += p.x * zv0 + p.y * zv1 + p.z * zv2 + p.w * zv3;
            }
        }
    }
    __syncthreads();   // all phase-B reads of z_s done before red reuse

    // ---- cross-wave reduce (reuse z_s region), single atomic per slot ----
    float* red = &z_s[0][0];    // 4*20*64 = 5120 floats <= 128*68
    #pragma unroll
    for (int k = 0; k < KK; ++k) red[(q * KK + k) * 64 + lane] = pacc[k];
    #pragma unroll
    for (int off = 16; off >= 1; off >>= 1) {
        #pragma unroll
        for (int i = 0; i < 10; ++i) nkp[i] += __shfl_down(nkp[i], off);
    }
    if (j == 0) {
        #pragma unroll
        for (int i = 0; i < 10; ++i) nkred[q][h * 10 + i] = nkp[i];
    }
    __syncthreads();
    for (int idx = t; idx < KK * 64; idx += 256) {
        int k = idx >> 6, l = idx & 63;
        float sum = red[k * 64 + l] + red[(KK + k) * 64 + l]
                  + red[(2 * KK + k) * 64 + l] + red[(3 * KK + k) * 64 + l];
        atomicAdd(&macc[((size_t)b * KK + k) * LL + l], sum);
    }
    if (t < KK) {
        float sum = nkred[0][t] + nkred[1][t] + nkred[2][t] + nkred[3][t];
        atomicAdd(&nk[b * KK + t], sum);
    }
}

// Per (b,k): pi = Nk/N, mean = (macc/Nk) @ M, bias for next iter, re-zero acc.
__global__ __launch_bounds__(64) void k_final(const float* __restrict__ Mm,
                                              const float* __restrict__ IA,
                                              float* __restrict__ nk,
                                              float* __restrict__ macc,
                                              float* __restrict__ bias,
                                              float* __restrict__ out_pi,
                                              float* __restrict__ out_mean,
                                              float* __restrict__ out_trace) {
    int k = blockIdx.x, b = blockIdx.y;
    int l = threadIdx.x;
    int bk = b * KK + k;
    __shared__ float sraw[64];
    __shared__ float smean[64];
    float Nk = nk[bk];
    if (Nk == 0.f) Nk = 1e-22f;
    float pi = Nk / (float)NN;
    float raw = macc[(size_t)bk * LL + l] / Nk;
    sraw[l] = raw;
    __syncthreads();
    float nm = 0.f;
    #pragma unroll 8
    for (int m = 0; m < 64; ++m) nm += sraw[m] * Mm[m * 64 + l];
    out_mean[(size_t)bk * LL + l] = nm;
    smean[l] = nm;
    __syncthreads();
    float cm = 0.f;
    #pragma unroll 8
    for (int m = 0; m < 64; ++m) cm += smean[m] * IA[m * 64 + l];
    float sqm = nm * nm;
    float sqc = cm * cm;
    for (int off = 32; off > 0; off >>= 1) {
        sqm += __shfl_down(sqm, off);
        sqc += __shfl_down(sqc, off);
    }
    if (l == 0) {
        bias[bk] = logf(pi) - 0.5f * (sqm + sqc);
        out_pi[bk] = pi;
        out_trace[bk] = 1.0f;
        nk[bk] = 0.f;
    }
    macc[(size_t)bk * LL + l] = 0.f;
}

extern "C" void kernel_launch(void* const* d_in, const int* in_sizes, int n_in,
                              void* d_out, int out_size, void* d_ws, size_t ws_size,
                              hipStream_t stream) {
    const float* z = (const float*)d_in[0];
    const float* A = (const float*)d_in[1];
    const int* idxs = (const int*)d_in[2];

    float* out_pi = (float*)d_out;
    float* out_mean = out_pi + BB * KK;
    float* out_trace = out_mean + (size_t)BB * KK * LL;

    float* ws = (float*)d_ws;
    float* IA = ws;
    float* M = ws + 4096;
    float* bias = ws + 8192;
    float* nk = ws + 9472;
    float* macc = ws + 10752;

    k_setup<<<1, 256, 0, stream>>>(A, IA, M);
    k_init<<<dim3(KK, BB), 64, 0, stream>>>(z, idxs, M, IA, out_mean, bias, nk, macc);
    for (int it = 0; it < 5; ++it) {
        k_empass<<<dim3(CHUNKS, BB), 256, 0, stream>>>(z, out_mean, bias, nk, macc);
        k_final<<<dim3(KK, BB), 64, 0, stream>>>(M, IA, nk, macc, bias, out_pi, out_mean, out_trace);
    }
}